// Round 2
// baseline (452.611 us; speedup 1.0000x reference)
//
#include <hip/hip_runtime.h>
#include <hip/hip_bf16.h>

#define BHN 128
#define LEN 512
#define DIM 64
#define QB 32
#define NTHR 512
#define SROW 520            // 512 + 8 bf16 pad -> rows shift banks, <=2-way alias
#define NEGF -1e12f

typedef __attribute__((ext_vector_type(8))) short bf16x8;   // MFMA A/B frag
typedef __attribute__((ext_vector_type(4))) float f32x4;    // MFMA C/D frag

__device__ __forceinline__ unsigned short f2bf(float x) {   // RNE f32->bf16
    unsigned int u = __builtin_bit_cast(unsigned int, x);
    u = (u + 0x7fffu + ((u >> 16) & 1u)) >> 16;
    return (unsigned short)u;
}
__device__ __forceinline__ float bf2f(unsigned short s) {
    return __builtin_bit_cast(float, ((unsigned int)s) << 16);
}
__device__ __forceinline__ bf16x8 pack8(float4 a, float4 b) {
    bf16x8 f;
    f[0]=(short)f2bf(a.x); f[1]=(short)f2bf(a.y); f[2]=(short)f2bf(a.z); f[3]=(short)f2bf(a.w);
    f[4]=(short)f2bf(b.x); f[5]=(short)f2bf(b.y); f[6]=(short)f2bf(b.z); f[7]=(short)f2bf(b.w);
    return f;
}

__global__ __launch_bounds__(NTHR, 4)
void attn_fused(const float* __restrict__ qg,
                const float* __restrict__ kg,
                const float* __restrict__ vg,
                const float* __restrict__ selg,
                const unsigned char* __restrict__ maskb,
                float* __restrict__ ctx_out,
                float* __restrict__ attn_out)
{
    __shared__ unsigned short s_tile[QB][SROW];   // qk (bf16), later P (bf16)
    __shared__ float pmax[QB][2];
    __shared__ float psum[QB][2];

    // XCD swizzle: hw round-robins blockIdx%8 across XCDs; remap so each XCD
    // owns a contiguous chunk of work -> all 16 q-blocks of a bh share one L2.
    int bid = blockIdx.x;
    int wid = (bid & 7) * (int)(gridDim.x >> 3) + (bid >> 3);
    const int bh = wid >> 4;
    const int q0 = (wid & 15) * QB;

    const int tid = threadIdx.x;
    const int w   = tid >> 6;      // wave 0..7
    const int l   = tid & 63;
    const int l15 = l & 15;
    const int lg  = l >> 4;        // 0..3 (k-group for MFMA frags)

    // ---- mask dtype detection: int32 0/1 words OR to <=1; bytes OR to 0x01010101
    unsigned int accm = 0;
    const unsigned int* mw = (const unsigned int*)maskb;
    #pragma unroll
    for (int i = 0; i < 16; ++i) accm |= mw[i];
    const bool int_mode = ((accm & 0xFFFFFFFEu) == 0);

    const float* qp = qg + (size_t)bh * LEN * DIM;
    const float* kp = kg + (size_t)bh * LEN * DIM;
    const float* vp = vg + (size_t)bh * LEN * DIM;

    // ================= Phase 1: S = (Q K^T) * scale -> bf16 LDS =================
    // wave w: q-tile (w>>2) [16 rows], kc range (w&3)*128 [8 tiles of 16]
    const int qtile  = w >> 2;
    const int kcbase = (w & 3) * 128;

    bf16x8 afrag[2];
    #pragma unroll
    for (int ks = 0; ks < 2; ++ks) {
        const float* ap = qp + (size_t)(q0 + qtile * 16 + l15) * DIM + ks * 32 + lg * 8;
        afrag[ks] = pack8(*(const float4*)ap, *(const float4*)(ap + 4));
    }

    f32x4 acc[8];
    #pragma unroll
    for (int kt = 0; kt < 8; ++kt) acc[kt] = (f32x4){0.f, 0.f, 0.f, 0.f};

    #pragma unroll 4
    for (int kt = 0; kt < 8; ++kt) {
        const int kc = kcbase + kt * 16 + l15;
        const float* bp = kp + (size_t)kc * DIM + lg * 8;
        #pragma unroll
        for (int ks = 0; ks < 2; ++ks) {
            bf16x8 bfrag = pack8(*(const float4*)(bp + ks * 32),
                                 *(const float4*)(bp + ks * 32 + 4));
            acc[kt] = __builtin_amdgcn_mfma_f32_16x16x32_bf16(afrag[ks], bfrag, acc[kt], 0, 0, 0);
        }
    }
    // epilogue: D[row=(lg)*4+r][col=l15] ; apply scale, store bf16
    #pragma unroll
    for (int kt = 0; kt < 8; ++kt) {
        const int kc = kcbase + kt * 16 + l15;
        const int qr = qtile * 16 + lg * 4;
        #pragma unroll
        for (int r = 0; r < 4; ++r)
            s_tile[qr + r][kc] = f2bf(acc[kt][r] * 0.125f);
    }
    __syncthreads();

    // ========== Phase 2: +selector, mask, softmax, write attn, P->LDS ==========
    const size_t selbase = (size_t)bh * LEN * LEN + (size_t)q0 * LEN;
    const float* selp = selg + selbase;
    float*      attnp = attn_out + selbase;
    const unsigned char* mb8 = maskb + selbase;
    const int*          mb32 = (const int*)maskb + selbase;

    f32x4 sv[8];
    // pass i: each wave handles one full row r, cols (w&1)*256 + l*4
    #pragma unroll
    for (int i = 0; i < 8; ++i) {
        const int ci  = tid + NTHR * i;
        const int r   = ci >> 7;
        const int col = (ci & 127) * 4;
        ushort4 sq = *(const ushort4*)&s_tile[r][col];
        float4  se = *(const float4*)(selp + (size_t)r * LEN + col);
        f32x4 x;
        x[0] = bf2f(sq.x) + se.x;  x[1] = bf2f(sq.y) + se.y;
        x[2] = bf2f(sq.z) + se.z;  x[3] = bf2f(sq.w) + se.w;
        if (int_mode) {
            int4 m4 = *(const int4*)(mb32 + (size_t)r * LEN + col);
            x[0] = m4.x ? x[0] : NEGF;  x[1] = m4.y ? x[1] : NEGF;
            x[2] = m4.z ? x[2] : NEGF;  x[3] = m4.w ? x[3] : NEGF;
        } else {
            uchar4 m4 = *(const uchar4*)(mb8 + (size_t)r * LEN + col);
            x[0] = m4.x ? x[0] : NEGF;  x[1] = m4.y ? x[1] : NEGF;
            x[2] = m4.z ? x[2] : NEGF;  x[3] = m4.w ? x[3] : NEGF;
        }
        sv[i] = x;
        float m = fmaxf(fmaxf(x[0], x[1]), fmaxf(x[2], x[3]));
        #pragma unroll
        for (int d = 32; d; d >>= 1) m = fmaxf(m, __shfl_xor(m, d, 64));
        if (l == 0) pmax[r][w & 1] = m;
    }
    __syncthreads();

    #pragma unroll
    for (int i = 0; i < 8; ++i) {
        const int ci  = tid + NTHR * i;
        const int r   = ci >> 7;
        const int col = (ci & 127) * 4;
        const float m = fmaxf(pmax[r][0], pmax[r][1]);
        f32x4 x = sv[i];
        f32x4 e;
        e[0] = __expf(x[0] - m);  e[1] = __expf(x[1] - m);
        e[2] = __expf(x[2] - m);  e[3] = __expf(x[3] - m);
        sv[i] = e;
        ushort4 eb;
        eb.x = f2bf(e[0]); eb.y = f2bf(e[1]); eb.z = f2bf(e[2]); eb.w = f2bf(e[3]);
        *(ushort4*)&s_tile[r][col] = eb;                 // P (bf16), 1:1 slots
        float s = e[0] + e[1] + e[2] + e[3];
        #pragma unroll
        for (int d = 32; d; d >>= 1) s += __shfl_xor(s, d, 64);
        if (l == 0) psum[r][w & 1] = s;
    }
    __syncthreads();

    #pragma unroll
    for (int i = 0; i < 8; ++i) {
        const int ci  = tid + NTHR * i;
        const int r   = ci >> 7;
        const int col = (ci & 127) * 4;
        const float inv = 1.0f / (psum[r][0] + psum[r][1]);
        f32x4 e = sv[i];
        float4 o;
        o.x = e[0] * inv;  o.y = e[1] * inv;  o.z = e[2] * inv;  o.w = e[3] * inv;
        *(float4*)(attnp + (size_t)r * LEN + col) = o;    // coalesced f32 attn
    }

    // ================= Phase 3: context = (P @ V) / rowsum (MFMA) =================
    // wave w: q-tile (w>>2), d-tile (w&3)*16 ; K=512 in 16 steps of 32
    const int dtile = (w & 3) * 16;
    f32x4 pacc = (f32x4){0.f, 0.f, 0.f, 0.f};
    #pragma unroll 4
    for (int ks = 0; ks < 16; ++ks) {
        bf16x8 a = *(const bf16x8*)&s_tile[qtile * 16 + l15][ks * 32 + lg * 8];
        const float* vb = vp + (size_t)(ks * 32 + lg * 8) * DIM + dtile + l15;
        bf16x8 b;
        #pragma unroll
        for (int j = 0; j < 8; ++j) b[j] = (short)f2bf(vb[(size_t)j * DIM]);
        pacc = __builtin_amdgcn_mfma_f32_16x16x32_bf16(a, b, pacc, 0, 0, 0);
    }
    float* cp = ctx_out + (size_t)bh * LEN * DIM
              + (size_t)(q0 + qtile * 16 + lg * 4) * DIM + dtile + l15;
    #pragma unroll
    for (int r = 0; r < 4; ++r) {
        const int row = qtile * 16 + lg * 4 + r;                 // row within QB block
        const float inv = 1.0f / (psum[row][0] + psum[row][1]);  // normalize P@V
        cp[(size_t)r * DIM] = pacc[r] * inv;
    }
}

extern "C" void kernel_launch(void* const* d_in, const int* in_sizes, int n_in,
                              void* d_out, int out_size, void* d_ws, size_t ws_size,
                              hipStream_t stream) {
    (void)in_sizes; (void)n_in; (void)d_ws; (void)ws_size; (void)out_size;
    const float* q   = (const float*)d_in[0];
    const float* k   = (const float*)d_in[1];
    const float* v   = (const float*)d_in[2];
    const float* sel = (const float*)d_in[3];
    const unsigned char* mask = (const unsigned char*)d_in[4];
    float* ctx  = (float*)d_out;
    float* attn = ctx + (size_t)BHN * LEN * DIM;   // outputs concatenated: context, attn
    attn_fused<<<dim3(BHN * (LEN / QB)), dim3(NTHR), 0, stream>>>(q, k, v, sel, mask, ctx, attn);
}